// Round 7
// baseline (584.040 us; speedup 1.0000x reference)
//
#include <hip/hip_runtime.h>
#include <cmath>

#define DI __device__ __forceinline__

typedef unsigned short ushort_t;
typedef __attribute__((ext_vector_type(8))) short short8;
typedef __attribute__((ext_vector_type(8))) unsigned short ushort8;
typedef __attribute__((ext_vector_type(4))) unsigned short ushort4_t;
typedef __attribute__((ext_vector_type(4))) float floatx4;
typedef unsigned int u32;

DI float bf2f(ushort_t u) {
    unsigned v = ((unsigned)u) << 16;
    float f;
    __builtin_memcpy(&f, &v, 4);
    return f;
}
DI ushort_t f2bf(float f) {  // RNE
    unsigned u;
    __builtin_memcpy(&u, &f, 4);
    unsigned r = (u + 0x7FFFu + ((u >> 16) & 1u)) >> 16;
    return (ushort_t)r;
}
DI ushort_t f2bf_tr(float f) {  // truncation: 1 VALU op
    unsigned u;
    __builtin_memcpy(&u, &f, 4);
    return (ushort_t)(u >> 16);
}

DI void async_copy16(const ushort_t* gsrc, ushort_t* ldst) {
    auto gp = (const __attribute__((address_space(1))) u32*)gsrc;
    auto lp = (__attribute__((address_space(3))) u32*)ldst;
    __builtin_amdgcn_global_load_lds(gp, lp, 16, 0, 0);
}

// B=16, C=256, H=W=56, HEADS=8, DHEAD=32, BLOCK=7, HALO=3, WIN=13, tokens=50176
// Inputs fp32, output fp32. Trunk (x -> x1 -> out) stays fp32; branches bf16.

// ---------------- fused fp32 -> bf16 weight conversion (one launch) ----------
__global__ void convert_all_kernel(const float* __restrict__ wq, const float* __restrict__ wkv,
                                   const float* __restrict__ wo, const float* __restrict__ fc1w,
                                   const float* __restrict__ fc2w, const float* __restrict__ relh,
                                   const float* __restrict__ relw,
                                   ushort_t* __restrict__ bqkv, ushort_t* __restrict__ woC,
                                   ushort_t* __restrict__ fc1C, ushort_t* __restrict__ fc2C,
                                   ushort_t* __restrict__ relC) {
    int i = blockIdx.x * 256 + threadIdx.x;
    if (i < 196608) { bqkv[i] = f2bf(i < 65536 ? wq[i] : wkv[i - 65536]); return; }
    i -= 196608;
    if (i < 65536) { woC[i] = f2bf(wo[i]); return; }
    i -= 65536;
    if (i < 262144) { fc1C[i] = f2bf(fc1w[i]); return; }
    i -= 262144;
    if (i < 262144) { fc2C[i] = f2bf(fc2w[i]); return; }
    i -= 262144;
    if (i < 800) { relC[i] = f2bf(relh[i]); return; }
    i -= 800;
    if (i < 800) relC[800 + i] = f2bf(relw[i]);
}

// ---------------- LN1: fp32 NCHW -> bf16 NHWC (t1) + fp32 NHWC copy (xh) -----
__global__ __launch_bounds__(256) void ln1_kernel(const float* __restrict__ x,
                                                  const float* __restrict__ w,
                                                  const float* __restrict__ bias,
                                                  ushort_t* __restrict__ t1,
                                                  float* __restrict__ xh) {
    __shared__ __align__(16) float lds[56 * 256];  // [w][c] = 56 KiB
    int b = blockIdx.x / 56, h = blockIdx.x % 56;
    int c = threadIdx.x;
    const float* row = x + (((size_t)(b * 256 + c) * 56 + h) * 56);
    floatx4 vals[14];
#pragma unroll
    for (int i = 0; i < 14; i++) vals[i] = *(const floatx4*)(row + i * 4);
#pragma unroll
    for (int i = 0; i < 14; i++)
#pragma unroll
        for (int e = 0; e < 4; e++) lds[(i * 4 + e) * 256 + c] = vals[i][e];
    __syncthreads();
    int wv = threadIdx.x >> 6, lane = threadIdx.x & 63;
    for (int p0 = 0; p0 < 14; p0++) {
        int p = wv * 14 + p0;
        float xv[4];
        float s = 0.f, q = 0.f;
#pragma unroll
        for (int j = 0; j < 4; j++) {
            xv[j] = lds[p * 256 + lane * 4 + j];
            s += xv[j];
            q += xv[j] * xv[j];
        }
#pragma unroll
        for (int off = 32; off; off >>= 1) {
            s += __shfl_xor(s, off);
            q += __shfl_xor(q, off);
        }
        float mean = s * (1.f / 256.f);
        float var = q * (1.f / 256.f) - mean * mean;
        float rstd = rsqrtf(var + 1e-6f);
        size_t token = ((size_t)b * 56 + h) * 56 + p;
        ushort4_t o4;
        floatx4 x4;
#pragma unroll
        for (int j = 0; j < 4; j++) {
            int cc = lane * 4 + j;
            o4[j] = f2bf(w[cc] * ((xv[j] - mean) * rstd) + bias[cc]);
            x4[j] = xv[j];
        }
        *(ushort4_t*)(t1 + token * 256 + lane * 4) = o4;
        *(floatx4*)(xh + token * 256 + lane * 4) = x4;
    }
}

// ---------------- GEMM  C(M,N) = A(M,K) @ Bw(N,K)^T + epilogue ----------------
// EPI 0: bf16 store. EPI 1: fp32 out = fp32res + gamma*(acc+bias) (in-place ok).
// EPI 2: bf16 gelu(acc+bias). EPI 3: bf16 store, cols<256 prescaled by 32^-0.5.
template <int EPI>
__global__ __launch_bounds__(256) void gemm_kernel(const ushort_t* __restrict__ A,
                                                   const ushort_t* __restrict__ Bw,
                                                   void* __restrict__ Cout, int K, int N,
                                                   const float* __restrict__ biasf,
                                                   const float* __restrict__ resf,
                                                   const float* __restrict__ gammaf) {
    __shared__ __align__(16) ushort_t As[128 * 32];
    __shared__ __align__(16) ushort_t Bs[128 * 32];
    int m0 = blockIdx.x * 128, n0 = blockIdx.y * 128;
    int t = threadIdx.x;
    int wave = t >> 6, lane = t & 63;
    int wm = (wave & 1) * 64, wn = (wave >> 1) * 64;
    int lr = lane & 15, quad = lane >> 4;
    floatx4 acc[4][4] = {};
    for (int k0 = 0; k0 < K; k0 += 32) {
#pragma unroll
        for (int i = 0; i < 2; i++) {
            int chunk = t + 256 * i;
            int row = chunk >> 2, c16 = chunk & 3;
            async_copy16(A + (size_t)(m0 + row) * K + k0 + c16 * 8, As + chunk * 8);
            async_copy16(Bw + (size_t)(n0 + row) * K + k0 + c16 * 8, Bs + chunk * 8);
        }
        __syncthreads();
        short8 af[4], bf[4];
#pragma unroll
        for (int i = 0; i < 4; i++) af[i] = *(const short8*)(As + (wm + i * 16 + lr) * 32 + quad * 8);
#pragma unroll
        for (int i = 0; i < 4; i++) bf[i] = *(const short8*)(Bs + (wn + i * 16 + lr) * 32 + quad * 8);
#pragma unroll
        for (int i = 0; i < 4; i++)
#pragma unroll
            for (int j = 0; j < 4; j++)
                acc[i][j] = __builtin_amdgcn_mfma_f32_16x16x32_bf16(af[i], bf[j], acc[i][j], 0, 0, 0);
        __syncthreads();
    }
    const float qsc = (EPI == 3 && n0 < 256) ? 0.17677669529663687f : 1.0f;
#pragma unroll
    for (int i = 0; i < 4; i++)
#pragma unroll
        for (int j = 0; j < 4; j++)
#pragma unroll
            for (int r = 0; r < 4; r++) {
                int row = m0 + wm + i * 16 + quad * 4 + r;
                int col = n0 + wn + j * 16 + lr;
                float v = acc[i][j][r];
                if (EPI == 1) {
                    v = resf[(size_t)row * N + col] + gammaf[col] * (v + biasf[col]);
                    ((float*)Cout)[(size_t)row * N + col] = v;
                } else if (EPI == 2) {
                    v += biasf[col];
                    v = 0.5f * v * (1.0f + erff(v * 0.70710678118654752f));
                    ((ushort_t*)Cout)[(size_t)row * N + col] = f2bf(v);
                } else {
                    ((ushort_t*)Cout)[(size_t)row * N + col] = f2bf(v * qsc);
                }
            }
}

// ---------------- halo attention v3: VALU-lean ----------------
// Q prescaled by 32^-0.5 upstream. No max-subtraction (scores bounded).
// P unnormalized (inv applied to oacc). Trunc bf16 stores. Garbage q-rows
// 49..63 finite & masked at store. 5 wg/CU (LDS 32512 B).
__global__ __launch_bounds__(256, 5) void attn_kernel(const ushort_t* __restrict__ qkv,
                                                      const ushort_t* __restrict__ relh,
                                                      const ushort_t* __restrict__ relw,
                                                      ushort_t* __restrict__ attnout) {
    __shared__ __align__(16) char smem[32512];
    ushort_t* Vt = (ushort_t*)smem;             // 32 x 200 (cols 176..191 zeroed)
    ushort_t* tbl = (ushort_t*)(smem + 12800);  // 64 x 50 bf16
    ushort_t* Ks = (ushort_t*)(smem + 19200);   // 176 x 32 (aliased by Ps)
    ushort_t* Ps = (ushort_t*)(smem + 19200);   // 64 x 104 (after barrier2)

    int wg = blockIdx.x;
    int head = wg & 7;
    int blk = (wg >> 3) & 63;
    int b = wg >> 9;
    int bh = blk >> 3, bw = blk & 7;
    int t = threadIdx.x;
    int wave = t >> 6, lane = t & 63;
    int lr = lane & 15, quad = lane >> 4;
    const int base_tok = b * 3136;

    // --- stage K: 704 async 16B chunks, LDS [j][32] contiguous ---
    for (int c = t; c < 704; c += 256) {
        int j = c >> 2, ck = c & 3;
        int kh = j / 13, kw = j - kh * 13;
        int gh = bh * 7 + kh - 3, gw = bw * 7 + kw - 3;
        int tok = base_tok + gh * 56 + gw;
        tok = min(max(tok, 0), 50175);
        async_copy16(qkv + (size_t)tok * 768 + 256 + head * 32 + ck * 8, Ks + c * 8);
    }
    // --- stage V transposed: vector load + register scatter (j-fast: conflict-free) ---
    for (int c = t; c < 704; c += 256) {
        int ck = (c >= 528) ? 3 : (c >= 352) ? 2 : (c >= 176) ? 1 : 0;
        int j = c - ck * 176;
        int kh = j / 13, kw = j - kh * 13;
        int gh = bh * 7 + kh - 3, gw = bw * 7 + kw - 3;
        int tok = base_tok + gh * 56 + gw;
        tok = min(max(tok, 0), 50175);
        ushort8 v = *(const ushort8*)(qkv + (size_t)tok * 768 + 512 + head * 32 + ck * 8);
#pragma unroll
        for (int e = 0; e < 8; e++) Vt[(ck * 8 + e) * 200 + j] = v[e];
    }
    // zero-pad Vt cols 176..191
    {
        int row = t >> 3, e2 = t & 7;
        *(u32*)(Vt + row * 200 + 176 + e2 * 2) = 0;
    }
    // --- Q fragment directly from global ---
    short8 aq;
    {
        int qrow = wave * 16 + lr;
        int qx = qrow / 7, qy = qrow - qx * 7;
        int tok = min(base_tok + (bh * 7 + qx) * 56 + (bw * 7 + qy), 50175);
        aq = *(const short8*)(qkv + (size_t)tok * 768 + head * 32 + quad * 8);
    }
    __syncthreads();  // barrier1: staging complete

    floatx4 zero4 = {0.f, 0.f, 0.f, 0.f};

    // --- relative-bias table (wave-private rows; trunc stores) ---
#pragma unroll
    for (int ntile = 0; ntile < 4; ntile++) {
        int n = ntile * 16 + lr;
        int eff = (n < 50) ? n : 0;
        const ushort_t* rp = (eff < 25) ? (relh + eff * 32) : (relw + (eff - 25) * 32);
        short8 bfg = *(const short8*)(rp + quad * 8);
        floatx4 cta = __builtin_amdgcn_mfma_f32_16x16x32_bf16(aq, bfg, zero4, 0, 0, 0);
#pragma unroll
        for (int r = 0; r < 4; r++)
            if (n < 50) tbl[(wave * 16 + quad * 4 + r) * 50 + n] = f2bf_tr(cta[r]);
    }

    // --- QK^T ---
    floatx4 sacc[11];
#pragma unroll
    for (int nt = 0; nt < 11; nt++) {
        short8 bk = *(const short8*)(Ks + (nt * 16 + lr) * 32 + quad * 8);
        sacc[nt] = __builtin_amdgcn_mfma_f32_16x16x32_bf16(aq, bk, zero4, 0, 0, 0);
    }

    __syncthreads();  // barrier2: Ks free before Ps overwrites

    // --- per-column bias indices + mask addend (r-independent) ---
    int kh_a[11], kw_a[11];
    float madd[11];
    bool interior = (bh - 1u < 6u) && (bw - 1u < 6u);
    if (interior) {
#pragma unroll
        for (int nt = 0; nt < 11; nt++) {
            int j = nt * 16 + lr;
            int kh = j / 13;
            kh_a[nt] = kh;
            kw_a[nt] = j - kh * 13;
            madd[nt] = 0.f;
        }
        madd[10] = (160 + lr < 169) ? 0.f : -1e9f;
    } else {
#pragma unroll
        for (int nt = 0; nt < 11; nt++) {
            int j = nt * 16 + lr;
            int kh = j / 13, kw = j - kh * 13;
            int gh = bh * 7 + kh - 3, gw = bw * 7 + kw - 3;
            kh_a[nt] = kh;
            kw_a[nt] = kw;
            madd[nt] = ((j < 169) && ((unsigned)gh < 56u) && ((unsigned)gw < 56u)) ? 0.f : -1e9f;
        }
    }

    // --- softmax (no max-sub; unnormalized P) ---
    float pv[11][4];
    float inv_[4];
#pragma unroll
    for (int r = 0; r < 4; r++) {
        int qr2 = wave * 16 + quad * 4 + r;
        int qx = qr2 / 7, qy = qr2 - qx * 7;
        const ushort_t* th = tbl + qr2 * 50 + (12 - qx);
        const ushort_t* tw = tbl + qr2 * 50 + (37 - qy);
        float sum = 0.f;
#pragma unroll
        for (int nt = 0; nt < 11; nt++) {
            float bias = bf2f(th[kh_a[nt]]) + bf2f(tw[kw_a[nt]]);
            float e = __expf(sacc[nt][r] + bias + madd[nt]);
            pv[nt][r] = e;
            sum += e;
        }
#pragma unroll
        for (int off = 1; off < 16; off <<= 1) sum += __shfl_xor(sum, off);
        inv_[r] = 1.f / sum;
    }

    // --- PV in two halves over half-size wave-private Ps ---
    floatx4 oacc[2] = {zero4, zero4};
#pragma unroll
    for (int r = 0; r < 4; r++) {
        int qr2 = wave * 16 + quad * 4 + r;
#pragma unroll
        for (int nt = 0; nt < 6; nt++) Ps[qr2 * 104 + nt * 16 + lr] = f2bf_tr(pv[nt][r]);
    }
#pragma unroll
    for (int kk = 0; kk < 3; kk++) {
        int k0 = kk * 32;
        short8 ap = *(const short8*)(Ps + (wave * 16 + lr) * 104 + k0 + quad * 8);
#pragma unroll
        for (int n2 = 0; n2 < 2; n2++) {
            short8 bv = *(const short8*)(Vt + (n2 * 16 + lr) * 200 + k0 + quad * 8);
            oacc[n2] = __builtin_amdgcn_mfma_f32_16x16x32_bf16(ap, bv, oacc[n2], 0, 0, 0);
        }
    }
#pragma unroll
    for (int r = 0; r < 4; r++) {
        int qr2 = wave * 16 + quad * 4 + r;
#pragma unroll
        for (int nt = 6; nt < 11; nt++) Ps[qr2 * 104 + (nt * 16 - 96) + lr] = f2bf_tr(pv[nt][r]);
        Ps[qr2 * 104 + 80 + lr] = 0;
    }
#pragma unroll
    for (int kk = 0; kk < 3; kk++) {
        int k0 = kk * 32;
        short8 ap = *(const short8*)(Ps + (wave * 16 + lr) * 104 + k0 + quad * 8);
#pragma unroll
        for (int n2 = 0; n2 < 2; n2++) {
            short8 bv = *(const short8*)(Vt + (n2 * 16 + lr) * 200 + 96 + k0 + quad * 8);
            oacc[n2] = __builtin_amdgcn_mfma_f32_16x16x32_bf16(ap, bv, oacc[n2], 0, 0, 0);
        }
    }

    // --- normalize + store ---
#pragma unroll
    for (int n2 = 0; n2 < 2; n2++)
#pragma unroll
        for (int r = 0; r < 4; r++) {
            int qr2 = wave * 16 + quad * 4 + r;
            if (qr2 < 49) {
                int qx = qr2 / 7, qy = qr2 - qx * 7;
                size_t tok = (size_t)base_tok + (bh * 7 + qx) * 56 + (bw * 7 + qy);
                attnout[tok * 256 + head * 32 + n2 * 16 + lr] = f2bf(oacc[n2][r] * inv_[r]);
            }
        }
}

// ---------------- LN2: fp32 NHWC -> bf16 NHWC ----------------
__global__ __launch_bounds__(256) void ln2_kernel(const float* __restrict__ xin,
                                                  const float* __restrict__ w,
                                                  const float* __restrict__ bias,
                                                  ushort_t* __restrict__ o) {
    int token = blockIdx.x * 4 + (threadIdx.x >> 6);
    int lane = threadIdx.x & 63;
    floatx4 v4 = *(const floatx4*)(xin + (size_t)token * 256 + lane * 4);
    float s = 0.f, q = 0.f;
#pragma unroll
    for (int i = 0; i < 4; i++) {
        s += v4[i];
        q += v4[i] * v4[i];
    }
#pragma unroll
    for (int off = 32; off; off >>= 1) {
        s += __shfl_xor(s, off);
        q += __shfl_xor(q, off);
    }
    float mean = s * (1.f / 256.f);
    float var = q * (1.f / 256.f) - mean * mean;
    float rstd = rsqrtf(var + 1e-6f);
    ushort4_t o4;
#pragma unroll
    for (int i = 0; i < 4; i++) {
        int c = lane * 4 + i;
        o4[i] = f2bf(w[c] * ((v4[i] - mean) * rstd) + bias[c]);
    }
    *(ushort4_t*)(o + (size_t)token * 256 + lane * 4) = o4;
}

// ---------------- fp32 NHWC -> fp32 NCHW final transpose ----------------
__global__ __launch_bounds__(256) void out_transpose_kernel(const float* __restrict__ s,
                                                            float* __restrict__ o) {
    __shared__ __align__(16) float lds[56 * 256];
    int b = blockIdx.x / 56, h = blockIdx.x % 56;
    const float* src = s + (((size_t)b * 56 + h) * 56) * 256;
    int t = threadIdx.x;
#pragma unroll
    for (int i = 0; i < 14; i++) {
        int chunk = i * 256 + t;
        *(floatx4*)(lds + chunk * 4) = *(const floatx4*)(src + chunk * 4);
    }
    __syncthreads();
    int c = t;
    float* dst = o + (((size_t)b * 256 + c) * 56 + h) * 56;
#pragma unroll
    for (int i = 0; i < 14; i++) {
        floatx4 v;
#pragma unroll
        for (int e = 0; e < 4; e++) v[e] = lds[(i * 4 + e) * 256 + c];
        *(floatx4*)(dst + i * 4) = v;
    }
}

extern "C" void kernel_launch(void* const* d_in, const int* in_sizes, int n_in,
                              void* d_out, int out_size, void* d_ws, size_t ws_size,
                              hipStream_t stream) {
    const float* x = (const float*)d_in[0];
    const float* ln1w = (const float*)d_in[1];
    const float* ln1b = (const float*)d_in[2];
    const float* ln2w = (const float*)d_in[3];
    const float* ln2b = (const float*)d_in[4];
    const float* wq = (const float*)d_in[5];
    const float* wkv = (const float*)d_in[6];
    const float* wo = (const float*)d_in[7];
    const float* bo = (const float*)d_in[8];
    const float* relh = (const float*)d_in[9];
    const float* relw = (const float*)d_in[10];
    const float* g1 = (const float*)d_in[11];
    const float* g2 = (const float*)d_in[12];
    const float* fc1w = (const float*)d_in[13];
    const float* fc1b = (const float*)d_in[14];
    const float* fc2w = (const float*)d_in[15];
    const float* fc2b = (const float*)d_in[16];
    float* out = (float*)d_out;

    char* ws = (char*)d_ws;
    float* xh = (float*)ws;
    float* x1 = xh;
    float* sbuf = xh;
    ushort_t* t1 = (ushort_t*)(ws + 51380224);
    ushort_t* attnb = t1;
    ushort_t* qkv = (ushort_t*)(ws + 77070336);
    ushort_t* t2 = qkv;
    ushort_t* hid = (ushort_t*)(ws + 77070336 + 25690112);
    ushort_t* wv_ = (ushort_t*)(ws + 154140672);
    ushort_t* bqkv = wv_;
    ushort_t* woC = wv_ + 196608;
    ushort_t* fc1C = woC + 65536;
    ushort_t* fc2C = fc1C + 262144;
    ushort_t* relC = fc2C + 262144;

    convert_all_kernel<<<3079, 256, 0, stream>>>(wq, wkv, wo, fc1w, fc2w, relh, relw,
                                                 bqkv, woC, fc1C, fc2C, relC);
    ln1_kernel<<<896, 256, 0, stream>>>(x, ln1w, ln1b, t1, xh);
    gemm_kernel<3><<<dim3(392, 6), 256, 0, stream>>>(t1, bqkv, qkv, 256, 768, nullptr, nullptr, nullptr);
    attn_kernel<<<8192, 256, 0, stream>>>(qkv, relC, relC + 800, attnb);
    gemm_kernel<1><<<dim3(392, 2), 256, 0, stream>>>(attnb, woC, x1, 256, 256, bo, xh, g1);
    ln2_kernel<<<12544, 256, 0, stream>>>(x1, ln2w, ln2b, t2);
    const size_t CH = 25088;
    for (int c = 0; c < 2; c++) {
        gemm_kernel<2><<<dim3(196, 8), 256, 0, stream>>>(t2 + c * CH * 256, fc1C, hid, 256, 1024, fc1b, nullptr, nullptr);
        gemm_kernel<1><<<dim3(196, 2), 256, 0, stream>>>(hid, fc2C, sbuf + c * CH * 256, 1024, 256, fc2b, x1 + c * CH * 256, g2);
    }
    out_transpose_kernel<<<896, 256, 0, stream>>>(sbuf, out);
}

// Round 8
// 477.764 us; speedup vs baseline: 1.2224x; 1.2224x over previous
//
#include <hip/hip_runtime.h>
#include <cmath>

#define DI __device__ __forceinline__

typedef unsigned short ushort_t;
typedef __attribute__((ext_vector_type(8))) short short8;
typedef __attribute__((ext_vector_type(8))) unsigned short ushort8;
typedef __attribute__((ext_vector_type(4))) unsigned short ushort4_t;
typedef __attribute__((ext_vector_type(4))) float floatx4;
typedef unsigned int u32;

DI float bf2f(ushort_t u) {
    unsigned v = ((unsigned)u) << 16;
    float f;
    __builtin_memcpy(&f, &v, 4);
    return f;
}
DI ushort_t f2bf(float f) {  // RNE
    unsigned u;
    __builtin_memcpy(&u, &f, 4);
    unsigned r = (u + 0x7FFFu + ((u >> 16) & 1u)) >> 16;
    return (ushort_t)r;
}
DI ushort_t f2bf_tr(float f) {  // truncation: 1 VALU op
    unsigned u;
    __builtin_memcpy(&u, &f, 4);
    return (ushort_t)(u >> 16);
}

DI void async_copy16(const ushort_t* gsrc, ushort_t* ldst) {
    auto gp = (const __attribute__((address_space(1))) u32*)gsrc;
    auto lp = (__attribute__((address_space(3))) u32*)ldst;
    __builtin_amdgcn_global_load_lds(gp, lp, 16, 0, 0);
}

// B=16, C=256, H=W=56, HEADS=8, DHEAD=32, BLOCK=7, HALO=3, WIN=13, tokens=50176
// Inputs fp32, output fp32. Trunk (x -> x1 -> out) stays fp32; branches bf16.

// ---------------- fused fp32 -> bf16 weight conversion (one launch) ----------
__global__ void convert_all_kernel(const float* __restrict__ wq, const float* __restrict__ wkv,
                                   const float* __restrict__ wo, const float* __restrict__ fc1w,
                                   const float* __restrict__ fc2w, const float* __restrict__ relh,
                                   const float* __restrict__ relw,
                                   ushort_t* __restrict__ bqkv, ushort_t* __restrict__ woC,
                                   ushort_t* __restrict__ fc1C, ushort_t* __restrict__ fc2C,
                                   ushort_t* __restrict__ relC) {
    int i = blockIdx.x * 256 + threadIdx.x;
    if (i < 196608) { bqkv[i] = f2bf(i < 65536 ? wq[i] : wkv[i - 65536]); return; }
    i -= 196608;
    if (i < 65536) { woC[i] = f2bf(wo[i]); return; }
    i -= 65536;
    if (i < 262144) { fc1C[i] = f2bf(fc1w[i]); return; }
    i -= 262144;
    if (i < 262144) { fc2C[i] = f2bf(fc2w[i]); return; }
    i -= 262144;
    if (i < 800) { relC[i] = f2bf(relh[i]); return; }
    i -= 800;
    if (i < 800) relC[800 + i] = f2bf(relw[i]);
}

// ---------------- LN1: fp32 NCHW -> bf16 NHWC (t1) + fp32 NHWC copy (xh) -----
__global__ __launch_bounds__(256) void ln1_kernel(const float* __restrict__ x,
                                                  const float* __restrict__ w,
                                                  const float* __restrict__ bias,
                                                  ushort_t* __restrict__ t1,
                                                  float* __restrict__ xh) {
    __shared__ __align__(16) float lds[56 * 256];  // [w][c] = 56 KiB
    int b = blockIdx.x / 56, h = blockIdx.x % 56;
    int c = threadIdx.x;
    const float* row = x + (((size_t)(b * 256 + c) * 56 + h) * 56);
    floatx4 vals[14];
#pragma unroll
    for (int i = 0; i < 14; i++) vals[i] = *(const floatx4*)(row + i * 4);
#pragma unroll
    for (int i = 0; i < 14; i++)
#pragma unroll
        for (int e = 0; e < 4; e++) lds[(i * 4 + e) * 256 + c] = vals[i][e];
    __syncthreads();
    int wv = threadIdx.x >> 6, lane = threadIdx.x & 63;
    for (int p0 = 0; p0 < 14; p0++) {
        int p = wv * 14 + p0;
        float xv[4];
        float s = 0.f, q = 0.f;
#pragma unroll
        for (int j = 0; j < 4; j++) {
            xv[j] = lds[p * 256 + lane * 4 + j];
            s += xv[j];
            q += xv[j] * xv[j];
        }
#pragma unroll
        for (int off = 32; off; off >>= 1) {
            s += __shfl_xor(s, off);
            q += __shfl_xor(q, off);
        }
        float mean = s * (1.f / 256.f);
        float var = q * (1.f / 256.f) - mean * mean;
        float rstd = rsqrtf(var + 1e-6f);
        size_t token = ((size_t)b * 56 + h) * 56 + p;
        ushort4_t o4;
        floatx4 x4;
#pragma unroll
        for (int j = 0; j < 4; j++) {
            int cc = lane * 4 + j;
            o4[j] = f2bf(w[cc] * ((xv[j] - mean) * rstd) + bias[cc]);
            x4[j] = xv[j];
        }
        *(ushort4_t*)(t1 + token * 256 + lane * 4) = o4;
        *(floatx4*)(xh + token * 256 + lane * 4) = x4;
    }
}

// ---------------- GEMM  C(M,N) = A(M,K) @ Bw(N,K)^T + epilogue ----------------
// EPI 0: bf16 store. EPI 1: fp32 out = fp32res + gamma*(acc+bias) (in-place ok).
// EPI 2: bf16 gelu(acc+bias). EPI 3: bf16 store, cols<256 prescaled by 32^-0.5.
template <int EPI>
__global__ __launch_bounds__(256) void gemm_kernel(const ushort_t* __restrict__ A,
                                                   const ushort_t* __restrict__ Bw,
                                                   void* __restrict__ Cout, int K, int N,
                                                   const float* __restrict__ biasf,
                                                   const float* __restrict__ resf,
                                                   const float* __restrict__ gammaf) {
    __shared__ __align__(16) ushort_t As[128 * 32];
    __shared__ __align__(16) ushort_t Bs[128 * 32];
    int m0 = blockIdx.x * 128, n0 = blockIdx.y * 128;
    int t = threadIdx.x;
    int wave = t >> 6, lane = t & 63;
    int wm = (wave & 1) * 64, wn = (wave >> 1) * 64;
    int lr = lane & 15, quad = lane >> 4;
    floatx4 acc[4][4] = {};
    for (int k0 = 0; k0 < K; k0 += 32) {
#pragma unroll
        for (int i = 0; i < 2; i++) {
            int chunk = t + 256 * i;
            int row = chunk >> 2, c16 = chunk & 3;
            async_copy16(A + (size_t)(m0 + row) * K + k0 + c16 * 8, As + chunk * 8);
            async_copy16(Bw + (size_t)(n0 + row) * K + k0 + c16 * 8, Bs + chunk * 8);
        }
        __syncthreads();
        short8 af[4], bf[4];
#pragma unroll
        for (int i = 0; i < 4; i++) af[i] = *(const short8*)(As + (wm + i * 16 + lr) * 32 + quad * 8);
#pragma unroll
        for (int i = 0; i < 4; i++) bf[i] = *(const short8*)(Bs + (wn + i * 16 + lr) * 32 + quad * 8);
#pragma unroll
        for (int i = 0; i < 4; i++)
#pragma unroll
            for (int j = 0; j < 4; j++)
                acc[i][j] = __builtin_amdgcn_mfma_f32_16x16x32_bf16(af[i], bf[j], acc[i][j], 0, 0, 0);
        __syncthreads();
    }
    const float qsc = (EPI == 3 && n0 < 256) ? 0.17677669529663687f : 1.0f;
#pragma unroll
    for (int i = 0; i < 4; i++)
#pragma unroll
        for (int j = 0; j < 4; j++)
#pragma unroll
            for (int r = 0; r < 4; r++) {
                int row = m0 + wm + i * 16 + quad * 4 + r;
                int col = n0 + wn + j * 16 + lr;
                float v = acc[i][j][r];
                if (EPI == 1) {
                    v = resf[(size_t)row * N + col] + gammaf[col] * (v + biasf[col]);
                    ((float*)Cout)[(size_t)row * N + col] = v;
                } else if (EPI == 2) {
                    v += biasf[col];
                    v = 0.5f * v * (1.0f + erff(v * 0.70710678118654752f));
                    ((ushort_t*)Cout)[(size_t)row * N + col] = f2bf(v);
                } else {
                    ((ushort_t*)Cout)[(size_t)row * N + col] = f2bf(v * qsc);
                }
            }
}

// ---------------- halo attention v4: VALU-lean, spill-free ----------------
// Q prescaled by 32^-0.5 upstream. No max-subtraction. Unnormalized P.
// Ps half1 stored inside the per-r softmax loop; only 5 high tiles carried
// in regs (pvhi[5][4]) -> small live set, no scratch. launch_bounds (256,4):
// (256,5) in R7 forced VGPR=48 and spilled (WRITE_SIZE 25->443 MB).
__global__ __launch_bounds__(256, 4) void attn_kernel(const ushort_t* __restrict__ qkv,
                                                      const ushort_t* __restrict__ relh,
                                                      const ushort_t* __restrict__ relw,
                                                      ushort_t* __restrict__ attnout) {
    __shared__ __align__(16) char smem[32512];
    ushort_t* Vt = (ushort_t*)smem;             // 32 x 200 (cols 176..191 zeroed)
    ushort_t* tbl = (ushort_t*)(smem + 12800);  // 64 x 50 bf16
    ushort_t* Ks = (ushort_t*)(smem + 19200);   // 176 x 32 (aliased by Ps)
    ushort_t* Ps = (ushort_t*)(smem + 19200);   // 64 x 104 (after barrier2)

    int wg = blockIdx.x;
    int head = wg & 7;
    int blk = (wg >> 3) & 63;
    int b = wg >> 9;
    int bh = blk >> 3, bw = blk & 7;
    int t = threadIdx.x;
    int wave = t >> 6, lane = t & 63;
    int lr = lane & 15, quad = lane >> 4;
    const int base_tok = b * 3136;

    // --- stage K: 704 async 16B chunks, LDS [j][32] contiguous ---
    for (int c = t; c < 704; c += 256) {
        int j = c >> 2, ck = c & 3;
        int kh = j / 13, kw = j - kh * 13;
        int gh = bh * 7 + kh - 3, gw = bw * 7 + kw - 3;
        int tok = base_tok + gh * 56 + gw;
        tok = min(max(tok, 0), 50175);
        async_copy16(qkv + (size_t)tok * 768 + 256 + head * 32 + ck * 8, Ks + c * 8);
    }
    // --- stage V transposed: vector load + register scatter ---
    for (int c = t; c < 704; c += 256) {
        int ck = (c >= 528) ? 3 : (c >= 352) ? 2 : (c >= 176) ? 1 : 0;
        int j = c - ck * 176;
        int kh = j / 13, kw = j - kh * 13;
        int gh = bh * 7 + kh - 3, gw = bw * 7 + kw - 3;
        int tok = base_tok + gh * 56 + gw;
        tok = min(max(tok, 0), 50175);
        ushort8 v = *(const ushort8*)(qkv + (size_t)tok * 768 + 512 + head * 32 + ck * 8);
#pragma unroll
        for (int e = 0; e < 8; e++) Vt[(ck * 8 + e) * 200 + j] = v[e];
    }
    // zero-pad Vt cols 176..191
    {
        int row = t >> 3, e2 = t & 7;
        *(u32*)(Vt + row * 200 + 176 + e2 * 2) = 0;
    }
    // --- Q fragment directly from global ---
    short8 aq;
    {
        int qrow = wave * 16 + lr;
        int qx = qrow / 7, qy = qrow - qx * 7;
        int tok = min(base_tok + (bh * 7 + qx) * 56 + (bw * 7 + qy), 50175);
        aq = *(const short8*)(qkv + (size_t)tok * 768 + head * 32 + quad * 8);
    }
    __syncthreads();  // barrier1: staging complete

    floatx4 zero4 = {0.f, 0.f, 0.f, 0.f};

    // --- relative-bias table (wave-private rows; trunc stores) ---
#pragma unroll
    for (int ntile = 0; ntile < 4; ntile++) {
        int n = ntile * 16 + lr;
        int eff = (n < 50) ? n : 0;
        const ushort_t* rp = (eff < 25) ? (relh + eff * 32) : (relw + (eff - 25) * 32);
        short8 bfg = *(const short8*)(rp + quad * 8);
        floatx4 cta = __builtin_amdgcn_mfma_f32_16x16x32_bf16(aq, bfg, zero4, 0, 0, 0);
#pragma unroll
        for (int r = 0; r < 4; r++)
            if (n < 50) tbl[(wave * 16 + quad * 4 + r) * 50 + n] = f2bf_tr(cta[r]);
    }

    // --- QK^T ---
    floatx4 sacc[11];
#pragma unroll
    for (int nt = 0; nt < 11; nt++) {
        short8 bk = *(const short8*)(Ks + (nt * 16 + lr) * 32 + quad * 8);
        sacc[nt] = __builtin_amdgcn_mfma_f32_16x16x32_bf16(aq, bk, zero4, 0, 0, 0);
    }

    __syncthreads();  // barrier2: Ks free before Ps overwrites

    // --- per-column bias indices + mask addend (r-independent) ---
    int kh_a[11], kw_a[11];
    float madd[11];
    bool interior = (bh - 1u < 6u) && (bw - 1u < 6u);
    if (interior) {
#pragma unroll
        for (int nt = 0; nt < 11; nt++) {
            int j = nt * 16 + lr;
            int kh = j / 13;
            kh_a[nt] = kh;
            kw_a[nt] = j - kh * 13;
            madd[nt] = 0.f;
        }
        madd[10] = (160 + lr < 169) ? 0.f : -1e9f;
    } else {
#pragma unroll
        for (int nt = 0; nt < 11; nt++) {
            int j = nt * 16 + lr;
            int kh = j / 13, kw = j - kh * 13;
            int gh = bh * 7 + kh - 3, gw = bw * 7 + kw - 3;
            kh_a[nt] = kh;
            kw_a[nt] = kw;
            madd[nt] = ((j < 169) && ((unsigned)gh < 56u) && ((unsigned)gw < 56u)) ? 0.f : -1e9f;
        }
    }

    // --- softmax (no max-sub; unnormalized P); store low 6 tiles to Ps
    //     immediately, carry only high 5 tiles in regs ---
    float pvhi[5][4];
    float inv_[4];
#pragma unroll
    for (int r = 0; r < 4; r++) {
        int qr2 = wave * 16 + quad * 4 + r;
        int qx = qr2 / 7, qy = qr2 - qx * 7;
        const ushort_t* th = tbl + qr2 * 50 + (12 - qx);
        const ushort_t* tw = tbl + qr2 * 50 + (37 - qy);
        float sum = 0.f;
#pragma unroll
        for (int nt = 0; nt < 11; nt++) {
            float bias = bf2f(th[kh_a[nt]]) + bf2f(tw[kw_a[nt]]);
            float e = __expf(sacc[nt][r] + bias + madd[nt]);
            sum += e;
            if (nt < 6)
                Ps[qr2 * 104 + nt * 16 + lr] = f2bf_tr(e);
            else
                pvhi[nt - 6][r] = e;
        }
#pragma unroll
        for (int off = 1; off < 16; off <<= 1) sum += __shfl_xor(sum, off);
        inv_[r] = 1.f / sum;
    }

    // --- PV half 1: key cols 0..95 (Ps rows wave-private, already written) ---
    floatx4 oacc[2] = {zero4, zero4};
#pragma unroll
    for (int kk = 0; kk < 3; kk++) {
        int k0 = kk * 32;
        short8 ap = *(const short8*)(Ps + (wave * 16 + lr) * 104 + k0 + quad * 8);
#pragma unroll
        for (int n2 = 0; n2 < 2; n2++) {
            short8 bv = *(const short8*)(Vt + (n2 * 16 + lr) * 200 + k0 + quad * 8);
            oacc[n2] = __builtin_amdgcn_mfma_f32_16x16x32_bf16(ap, bv, oacc[n2], 0, 0, 0);
        }
    }
    // --- PV half 2: key cols 96..191 (cols 80..95 of buffer = keys 176.. -> 0) ---
#pragma unroll
    for (int r = 0; r < 4; r++) {
        int qr2 = wave * 16 + quad * 4 + r;
#pragma unroll
        for (int nt = 0; nt < 5; nt++) Ps[qr2 * 104 + nt * 16 + lr] = f2bf_tr(pvhi[nt][r]);
        Ps[qr2 * 104 + 80 + lr] = 0;
    }
#pragma unroll
    for (int kk = 0; kk < 3; kk++) {
        int k0 = kk * 32;
        short8 ap = *(const short8*)(Ps + (wave * 16 + lr) * 104 + k0 + quad * 8);
#pragma unroll
        for (int n2 = 0; n2 < 2; n2++) {
            short8 bv = *(const short8*)(Vt + (n2 * 16 + lr) * 200 + 96 + k0 + quad * 8);
            oacc[n2] = __builtin_amdgcn_mfma_f32_16x16x32_bf16(ap, bv, oacc[n2], 0, 0, 0);
        }
    }

    // --- normalize + store ---
#pragma unroll
    for (int n2 = 0; n2 < 2; n2++)
#pragma unroll
        for (int r = 0; r < 4; r++) {
            int qr2 = wave * 16 + quad * 4 + r;
            if (qr2 < 49) {
                int qx = qr2 / 7, qy = qr2 - qx * 7;
                size_t tok = (size_t)base_tok + (bh * 7 + qx) * 56 + (bw * 7 + qy);
                attnout[tok * 256 + head * 32 + n2 * 16 + lr] = f2bf(oacc[n2][r] * inv_[r]);
            }
        }
}

// ---------------- LN2: fp32 NHWC -> bf16 NHWC ----------------
__global__ __launch_bounds__(256) void ln2_kernel(const float* __restrict__ xin,
                                                  const float* __restrict__ w,
                                                  const float* __restrict__ bias,
                                                  ushort_t* __restrict__ o) {
    int token = blockIdx.x * 4 + (threadIdx.x >> 6);
    int lane = threadIdx.x & 63;
    floatx4 v4 = *(const floatx4*)(xin + (size_t)token * 256 + lane * 4);
    float s = 0.f, q = 0.f;
#pragma unroll
    for (int i = 0; i < 4; i++) {
        s += v4[i];
        q += v4[i] * v4[i];
    }
#pragma unroll
    for (int off = 32; off; off >>= 1) {
        s += __shfl_xor(s, off);
        q += __shfl_xor(q, off);
    }
    float mean = s * (1.f / 256.f);
    float var = q * (1.f / 256.f) - mean * mean;
    float rstd = rsqrtf(var + 1e-6f);
    ushort4_t o4;
#pragma unroll
    for (int i = 0; i < 4; i++) {
        int c = lane * 4 + i;
        o4[i] = f2bf(w[c] * ((v4[i] - mean) * rstd) + bias[c]);
    }
    *(ushort4_t*)(o + (size_t)token * 256 + lane * 4) = o4;
}

// ---------------- fp32 NHWC -> fp32 NCHW final transpose ----------------
__global__ __launch_bounds__(256) void out_transpose_kernel(const float* __restrict__ s,
                                                            float* __restrict__ o) {
    __shared__ __align__(16) float lds[56 * 256];
    int b = blockIdx.x / 56, h = blockIdx.x % 56;
    const float* src = s + (((size_t)b * 56 + h) * 56) * 256;
    int t = threadIdx.x;
#pragma unroll
    for (int i = 0; i < 14; i++) {
        int chunk = i * 256 + t;
        *(floatx4*)(lds + chunk * 4) = *(const floatx4*)(src + chunk * 4);
    }
    __syncthreads();
    int c = t;
    float* dst = o + (((size_t)b * 256 + c) * 56 + h) * 56;
#pragma unroll
    for (int i = 0; i < 14; i++) {
        floatx4 v;
#pragma unroll
        for (int e = 0; e < 4; e++) v[e] = lds[(i * 4 + e) * 256 + c];
        *(floatx4*)(dst + i * 4) = v;
    }
}

extern "C" void kernel_launch(void* const* d_in, const int* in_sizes, int n_in,
                              void* d_out, int out_size, void* d_ws, size_t ws_size,
                              hipStream_t stream) {
    const float* x = (const float*)d_in[0];
    const float* ln1w = (const float*)d_in[1];
    const float* ln1b = (const float*)d_in[2];
    const float* ln2w = (const float*)d_in[3];
    const float* ln2b = (const float*)d_in[4];
    const float* wq = (const float*)d_in[5];
    const float* wkv = (const float*)d_in[6];
    const float* wo = (const float*)d_in[7];
    const float* bo = (const float*)d_in[8];
    const float* relh = (const float*)d_in[9];
    const float* relw = (const float*)d_in[10];
    const float* g1 = (const float*)d_in[11];
    const float* g2 = (const float*)d_in[12];
    const float* fc1w = (const float*)d_in[13];
    const float* fc1b = (const float*)d_in[14];
    const float* fc2w = (const float*)d_in[15];
    const float* fc2b = (const float*)d_in[16];
    float* out = (float*)d_out;

    char* ws = (char*)d_ws;
    float* xh = (float*)ws;
    float* x1 = xh;
    float* sbuf = xh;
    ushort_t* t1 = (ushort_t*)(ws + 51380224);
    ushort_t* attnb = t1;
    ushort_t* qkv = (ushort_t*)(ws + 77070336);
    ushort_t* t2 = qkv;
    ushort_t* hid = (ushort_t*)(ws + 77070336 + 25690112);
    ushort_t* wv_ = (ushort_t*)(ws + 154140672);
    ushort_t* bqkv = wv_;
    ushort_t* woC = wv_ + 196608;
    ushort_t* fc1C = woC + 65536;
    ushort_t* fc2C = fc1C + 262144;
    ushort_t* relC = fc2C + 262144;

    convert_all_kernel<<<3079, 256, 0, stream>>>(wq, wkv, wo, fc1w, fc2w, relh, relw,
                                                 bqkv, woC, fc1C, fc2C, relC);
    ln1_kernel<<<896, 256, 0, stream>>>(x, ln1w, ln1b, t1, xh);
    gemm_kernel<3><<<dim3(392, 6), 256, 0, stream>>>(t1, bqkv, qkv, 256, 768, nullptr, nullptr, nullptr);
    attn_kernel<<<8192, 256, 0, stream>>>(qkv, relC, relC + 800, attnb);
    gemm_kernel<1><<<dim3(392, 2), 256, 0, stream>>>(attnb, woC, x1, 256, 256, bo, xh, g1);
    ln2_kernel<<<12544, 256, 0, stream>>>(x1, ln2w, ln2b, t2);
    const size_t CH = 25088;
    for (int c = 0; c < 2; c++) {
        gemm_kernel<2><<<dim3(196, 8), 256, 0, stream>>>(t2 + c * CH * 256, fc1C, hid, 256, 1024, fc1b, nullptr, nullptr);
        gemm_kernel<1><<<dim3(196, 2), 256, 0, stream>>>(hid, fc2C, sbuf + c * CH * 256, 1024, 256, fc2b, x1 + c * CH * 256, g2);
    }
    out_transpose_kernel<<<896, 256, 0, stream>>>(sbuf, out);
}